// Round 3
// baseline (164448.108 us; speedup 1.0000x reference)
//
#include <hip/hip_runtime.h>
#include <math.h>

#define TT 8192
#define HH 512
#define LL 5
#define OO 256
#define GG 48           // workgroups per layer
#define NTHR 256
#define RB 64           // h ring depth for layers 0..LL-2 (power of 2)
#define SPIN_CAP 50000000u   // watchdog: bail out of a stuck spin (anti-hang)

// ---------------- helpers ----------------

__device__ __forceinline__ float wred(float v) {
#pragma unroll
  for (int off = 32; off > 0; off >>= 1) v += __shfl_xor(v, off, 64);
  return v;
}

__device__ __forceinline__ float sigm(float v) {
  return 1.0f / (1.0f + expf(-v));
}

__device__ __forceinline__ void st_agent(float* p, float v) {
  __hip_atomic_store(p, v, __ATOMIC_RELAXED, __HIP_MEMORY_SCOPE_AGENT);
}
__device__ __forceinline__ float2 ld_agent2(const float* p) {
  unsigned long long u = __hip_atomic_load((const unsigned long long*)p,
                                           __ATOMIC_RELAXED, __HIP_MEMORY_SCOPE_AGENT);
  union { unsigned long long u; float2 f; } c; c.u = u;
  return c.f;
}

// bounded spin: true = flag observed, false = watchdog tripped
__device__ __forceinline__ bool wait_flag(unsigned char* f) {
  unsigned n = 0;
  while (__hip_atomic_load(f, __ATOMIC_ACQUIRE, __HIP_MEMORY_SCOPE_AGENT) == 0) {
    if (++n > SPIN_CAP) return false;
  }
  return true;
}

// ---------------- init: zero the flag arrays each call ----------------

__global__ void init_flags(unsigned* __restrict__ p, int n) {
  int stride = gridDim.x * blockDim.x;
  for (int i = blockIdx.x * blockDim.x + threadIdx.x; i < n; i += stride) p[i] = 0u;
}

// ---------------- persistent GRU pipeline ----------------
// grid: LL*GG = 240 blocks of 256 threads (<=256 CUs, 1 block/CU -> all
// co-resident). Block (l,g) owns ~10-11 of layer l's 512 rows; those rows of
// all six weight matrices live in VGPRs for all 8192 steps. Layers 0..LL-2
// publish h into a RB-deep ring (back-pressured); top layer writes full
// history (FC input). Dependencies are strictly lexicographic in (t, l):
//   wave0 waits (t, l-1) h; wave1 waits (t-1, l) h; wave2 waits (t-RB, l+1) h.

__launch_bounds__(NTHR, 1)
__global__ void gru_pipeline(
    const float* __restrict__ x,
    const float* __restrict__ Wz, const float* __restrict__ bWz,
    const float* __restrict__ Uz, const float* __restrict__ bUz,
    const float* __restrict__ Wr, const float* __restrict__ bWr,
    const float* __restrict__ Ur, const float* __restrict__ bUr,
    const float* __restrict__ Wh, const float* __restrict__ bWh,
    const float* __restrict__ Uh, const float* __restrict__ bUh,
    float* __restrict__ hring,         // [LL-1][RB][HH]
    float* __restrict__ htop,          // [TT][HH]
    float* __restrict__ rbuf,          // [LL][2][HH]
    unsigned char* __restrict__ rflg,  // [LL][TT][GG]
    unsigned char* __restrict__ hflg,  // [LL][TT][GG]
    float* __restrict__ dout)
{
  const int blk = blockIdx.x;
  const int l = blk / GG;
  const int g = blk % GG;
  const bool ltop = (l == LL - 1);
  const int base = HH / GG;            // 10
  const int rem = HH % GG;             // 32
  const int i0 = g * base + (g < rem ? g : rem);
  const int n_i = base + (g < rem ? 1 : 0);   // 10 or 11

  const int tid = threadIdx.x;
  const int wave = tid >> 6;
  const int lane = tid & 63;
  const int j0 = lane * 8;

  __shared__ float xs[HH];
  __shared__ float hs[HH];
  __shared__ float rh[HH];
  __shared__ volatile int dead;        // watchdog latch (anti-hang)
  if (tid == 0) dead = 0;

  // VGPR-resident weights: up to 3 rows per wave (rows r_loc = wave + 4k)
  float wz[3][8], uz[3][8], wr[3][8], ur[3][8], wh[3][8], uh[3][8];
  float bz[3], br[3], bh[3];
  int rowg[3];
  bool act[3];
#pragma unroll
  for (int k = 0; k < 3; ++k) {
    const int rl = wave + 4 * k;
    act[k] = (rl < n_i);
    const int i = i0 + (act[k] ? rl : 0);
    rowg[k] = i;
    if (act[k]) {
      const size_t ro = ((size_t)l * HH + i) * HH + j0;
      *(float4*)&wz[k][0] = *(const float4*)(Wz + ro);
      *(float4*)&wz[k][4] = *(const float4*)(Wz + ro + 4);
      *(float4*)&uz[k][0] = *(const float4*)(Uz + ro);
      *(float4*)&uz[k][4] = *(const float4*)(Uz + ro + 4);
      *(float4*)&wr[k][0] = *(const float4*)(Wr + ro);
      *(float4*)&wr[k][4] = *(const float4*)(Wr + ro + 4);
      *(float4*)&ur[k][0] = *(const float4*)(Ur + ro);
      *(float4*)&ur[k][4] = *(const float4*)(Ur + ro + 4);
      *(float4*)&wh[k][0] = *(const float4*)(Wh + ro);
      *(float4*)&wh[k][4] = *(const float4*)(Wh + ro + 4);
      *(float4*)&uh[k][0] = *(const float4*)(Uh + ro);
      *(float4*)&uh[k][4] = *(const float4*)(Uh + ro + 4);
      bz[k] = bWz[l * HH + i] + bUz[l * HH + i];
      br[k] = bWr[l * HH + i] + bUr[l * HH + i];
      bh[k] = bWh[l * HH + i] + bUh[l * HH + i];
    } else {
      bz[k] = br[k] = bh[k] = 0.f;
#pragma unroll
      for (int q = 0; q < 8; ++q) {
        wz[k][q] = uz[k][q] = wr[k][q] = ur[k][q] = wh[k][q] = uh[k][q] = 0.f;
      }
    }
  }

  unsigned char* my_hflg = hflg + (size_t)l * TT * GG;
  unsigned char* up_hflg = hflg + (size_t)(l > 0 ? l - 1 : 0) * TT * GG;
  unsigned char* dn_hflg = hflg + (size_t)(l < LL - 1 ? l + 1 : l) * TT * GG;
  unsigned char* my_rflg = rflg + (size_t)l * TT * GG;
  float* rb = rbuf + (size_t)l * 2 * HH;
  float* my_ring = hring + (size_t)l * RB * HH;          // valid for l<LL-1
  const float* up_ring = hring + (size_t)(l > 0 ? l - 1 : 0) * RB * HH;

  float zreg[3], awreg[3];
  zreg[0] = zreg[1] = zreg[2] = 0.f;
  awreg[0] = awreg[1] = awreg[2] = 0.f;

  __syncthreads();   // dead=0 visible

  for (int t = 0; t < TT; ++t) {
    // -------- wait for dependencies (watchdog-bounded) --------
    if (!dead) {
      if (wave == 0 && l > 0 && lane < GG) {
        if (!wait_flag(up_hflg + (size_t)t * GG + lane)) dead = 1;
      }
      if (wave == 1 && t > 0 && lane < GG) {
        if (!wait_flag(my_hflg + (size_t)(t - 1) * GG + lane)) dead = 1;
      }
      if (wave == 2 && !ltop && t >= RB && lane < GG) {
        if (!wait_flag(dn_hflg + (size_t)(t - RB) * GG + lane)) dead = 1;
      }
    }
    __syncthreads();

    // -------- stage x_in and h_prev into LDS --------
    {
      const int j = tid * 2;
      if (l == 0) {
        const float2 v = *(const float2*)&x[(size_t)t * HH + j];
        xs[j] = v.x; xs[j + 1] = v.y;
      } else {
        const float* src = up_ring + (size_t)(t & (RB - 1)) * HH;
        const float2 v = ld_agent2(&src[j]);
        xs[j] = v.x; xs[j + 1] = v.y;
      }
      if (t == 0) {
        hs[j] = 0.f; hs[j + 1] = 0.f;
      } else {
        const float* src = ltop ? htop + (size_t)(t - 1) * HH
                                : my_ring + (size_t)((t - 1) & (RB - 1)) * HH;
        const float2 v = ld_agent2(&src[j]);
        hs[j] = v.x; hs[j + 1] = v.y;
      }
    }
    __syncthreads();

    float xv[8], hv[8];
    *(float4*)&xv[0] = *(const float4*)&xs[j0];
    *(float4*)&xv[4] = *(const float4*)&xs[j0 + 4];
    *(float4*)&hv[0] = *(const float4*)&hs[j0];
    *(float4*)&hv[4] = *(const float4*)&hs[j0 + 4];

    float* rslot = rb + (size_t)(t & 1) * HH;
    float* hout = ltop ? htop + (size_t)t * HH
                       : my_ring + (size_t)(t & (RB - 1)) * HH;

    // -------- phase 1: z, r, Wh·x for owned rows --------
#pragma unroll
    for (int k = 0; k < 3; ++k) {
      if (act[k]) {
        float az = 0.f, ar = 0.f, aw = 0.f;
#pragma unroll
        for (int q = 0; q < 8; ++q) {
          az = fmaf(wz[k][q], xv[q], az);
          az = fmaf(uz[k][q], hv[q], az);
          ar = fmaf(wr[k][q], xv[q], ar);
          ar = fmaf(ur[k][q], hv[q], ar);
          aw = fmaf(wh[k][q], xv[q], aw);
        }
        az = wred(az); ar = wred(ar); aw = wred(aw);
        if (lane == 0) {
          const float z = sigm(az + bz[k]);
          zreg[k] = z;
          awreg[k] = aw + bh[k];
          if (t == 0) {
            const float hnew = z * tanhf(awreg[k]);   // h_prev = 0
            st_agent(&hout[rowg[k]], hnew);
          } else {
            const float r = sigm(ar + br[k]);
            st_agent(&rslot[rowg[k]], r);
          }
        }
      }
    }

    if (t == 0) {
      __syncthreads();
      if (tid == 0)
        __hip_atomic_store(&my_hflg[(size_t)0 * GG + g], (unsigned char)1,
                           __ATOMIC_RELEASE, __HIP_MEMORY_SCOPE_AGENT);
      continue;
    }

    // -------- r barrier across the layer's workgroups --------
    __syncthreads();   // all r stores drained before flag
    if (tid == 0)
      __hip_atomic_store(&my_rflg[(size_t)t * GG + g], (unsigned char)1,
                         __ATOMIC_RELEASE, __HIP_MEMORY_SCOPE_AGENT);
    if (!dead && wave == 0 && lane < GG) {
      if (!wait_flag(my_rflg + (size_t)t * GG + lane)) dead = 1;
    }
    __syncthreads();

    // -------- r ⊙ h_prev into LDS --------
    {
      const int j = tid * 2;
      const float2 rv = ld_agent2(&rslot[j]);
      rh[j] = rv.x * hs[j];
      rh[j + 1] = rv.y * hs[j + 1];
    }
    __syncthreads();

    float rhv[8];
    *(float4*)&rhv[0] = *(const float4*)&rh[j0];
    *(float4*)&rhv[4] = *(const float4*)&rh[j0 + 4];

    // -------- phase 2: Uh·(r⊙h), gate combine, publish h --------
#pragma unroll
    for (int k = 0; k < 3; ++k) {
      if (act[k]) {
        float u = 0.f;
#pragma unroll
        for (int q = 0; q < 8; ++q) u = fmaf(uh[k][q], rhv[q], u);
        u = wred(u);
        if (lane == 0) {
          const float z = zreg[k];
          const float hp = hs[rowg[k]];
          const float ht = tanhf(awreg[k] + u);
          const float hnew = (1.f - z) * hp + z * ht;
          st_agent(&hout[rowg[k]], hnew);
          if (t == TT - 1) dout[(size_t)TT * OO + (size_t)l * HH + rowg[k]] = hnew;
        }
      }
    }
    __syncthreads();
    if (tid == 0)
      __hip_atomic_store(&my_hflg[(size_t)t * GG + g], (unsigned char)1,
                         __ATOMIC_RELEASE, __HIP_MEMORY_SCOPE_AGENT);
  }
}

// ---------------- final FC: out[T,O] = outs[T,H] @ fcW[O,H]^T + fcb ----------------

__launch_bounds__(256)
__global__ void fc_gemm(const float* __restrict__ A,   // [TT][HH] (top-layer h)
                        const float* __restrict__ W,   // [OO][HH]
                        const float* __restrict__ bias, // [OO]
                        float* __restrict__ C) {       // [TT][OO]
  __shared__ float As[16][68];
  __shared__ float Ws[16][68];
  const int bm = blockIdx.x;        // TT/64
  const int bn = blockIdx.y;        // OO/64
  const int tid = threadIdx.x;
  const int tx = tid & 15;
  const int ty = tid >> 4;
  const int r = tid >> 2;           // 0..63
  const int kc = (tid & 3) * 4;     // 0,4,8,12
  float acc[4][4];
#pragma unroll
  for (int a = 0; a < 4; ++a)
#pragma unroll
    for (int b2 = 0; b2 < 4; ++b2) acc[a][b2] = 0.f;

  for (int k0 = 0; k0 < HH; k0 += 16) {
    const float4 a4 = *(const float4*)&A[(size_t)(bm * 64 + r) * HH + k0 + kc];
    const float4 w4 = *(const float4*)&W[(size_t)(bn * 64 + r) * HH + k0 + kc];
    __syncthreads();
    As[kc + 0][r] = a4.x; As[kc + 1][r] = a4.y; As[kc + 2][r] = a4.z; As[kc + 3][r] = a4.w;
    Ws[kc + 0][r] = w4.x; Ws[kc + 1][r] = w4.y; Ws[kc + 2][r] = w4.z; Ws[kc + 3][r] = w4.w;
    __syncthreads();
#pragma unroll
    for (int kk = 0; kk < 16; ++kk) {
      const float4 av = *(const float4*)&As[kk][ty * 4];
      const float4 wv = *(const float4*)&Ws[kk][tx * 4];
      const float avv[4] = {av.x, av.y, av.z, av.w};
      const float wvv[4] = {wv.x, wv.y, wv.z, wv.w};
#pragma unroll
      for (int a = 0; a < 4; ++a)
#pragma unroll
        for (int b2 = 0; b2 < 4; ++b2)
          acc[a][b2] = fmaf(avv[a], wvv[b2], acc[a][b2]);
    }
  }
#pragma unroll
  for (int a = 0; a < 4; ++a) {
    const int row = bm * 64 + ty * 4 + a;
#pragma unroll
    for (int b2 = 0; b2 < 4; ++b2) {
      const int col = bn * 64 + tx * 4 + b2;
      C[(size_t)row * OO + col] = acc[a][b2] + bias[col];
    }
  }
}

// ---------------- launch ----------------

extern "C" void kernel_launch(void* const* d_in, const int* in_sizes, int n_in,
                              void* d_out, int out_size, void* d_ws, size_t ws_size,
                              hipStream_t stream) {
  const float* p[15];
  for (int i = 0; i < 15 && i < n_in; ++i) p[i] = (const float*)d_in[i];

  const float *x, *Wz, *bWz, *Uz, *bUz, *Wr, *bWr, *Ur, *bUr, *Wh, *bWh, *Uh, *bUh, *fcW, *fcb;
  x = p[0];
  if (in_sizes[2] == LL * HH) {
    // setup_inputs() dict order: x, Wz, bWz, Uz, bUz, Wr, bWr, Ur, bUr, Wh, bWh, Uh, bUh, fcW, fcb
    Wz = p[1]; bWz = p[2]; Uz = p[3]; bUz = p[4];
    Wr = p[5]; bWr = p[6]; Ur = p[7]; bUr = p[8];
    Wh = p[9]; bWh = p[10]; Uh = p[11]; bUh = p[12];
  } else {
    // signature order fallback: x, Wz, Uz, Wr, Ur, Wh, Uh, bWz, bUz, bWr, bUr, bWh, bUh
    Wz = p[1]; Uz = p[2]; Wr = p[3]; Ur = p[4]; Wh = p[5]; Uh = p[6];
    bWz = p[7]; bUz = p[8]; bWr = p[9]; bUr = p[10]; bWh = p[11]; bUh = p[12];
  }
  fcW = p[13]; fcb = p[14];

  // workspace layout (~20.5 MB total; rings instead of full per-layer history)
  float* hring = (float*)d_ws;                                   // (LL-1)*RB*HH
  float* htop = hring + (size_t)(LL - 1) * RB * HH;              // TT*HH
  float* rbuf = htop + (size_t)TT * HH;                          // LL*2*HH
  unsigned char* rflg = (unsigned char*)(rbuf + (size_t)LL * 2 * HH);  // LL*TT*GG
  unsigned char* hflg = rflg + (size_t)LL * TT * GG;                   // LL*TT*GG

  const int flag_u32 = (int)(2 * (size_t)LL * TT * GG / 4);
  init_flags<<<512, 256, 0, stream>>>((unsigned*)rflg, flag_u32);

  gru_pipeline<<<LL * GG, NTHR, 0, stream>>>(
      x, Wz, bWz, Uz, bUz, Wr, bWr, Ur, bUr, Wh, bWh, Uh, bUh,
      hring, htop, rbuf, rflg, hflg, (float*)d_out);

  fc_gemm<<<dim3(TT / 64, OO / 64), 256, 0, stream>>>(
      htop, fcW, fcb, (float*)d_out);
}

// Round 4
// 164099.280 us; speedup vs baseline: 1.0021x; 1.0021x over previous
//
#include <hip/hip_runtime.h>
#include <math.h>

#define TT 8192
#define HH 512
#define LL 5
#define OO 256
#define GG 48           // workgroups per layer
#define NTHR 256
#define RB 64           // h ring depth for layers 0..LL-2 (power of 2)
#define SPIN_CAP 50000000u   // watchdog: bail out of a stuck spin (anti-hang)

// ---------------- helpers ----------------

__device__ __forceinline__ float wred(float v) {
#pragma unroll
  for (int off = 32; off > 0; off >>= 1) v += __shfl_xor(v, off, 64);
  return v;
}

__device__ __forceinline__ float sigm(float v) {
  return 1.0f / (1.0f + expf(-v));
}

__device__ __forceinline__ void st_agent(float* p, float v) {
  __hip_atomic_store(p, v, __ATOMIC_RELAXED, __HIP_MEMORY_SCOPE_AGENT);
}
__device__ __forceinline__ float2 ld_agent2(const float* p) {
  unsigned long long u = __hip_atomic_load((const unsigned long long*)p,
                                           __ATOMIC_RELAXED, __HIP_MEMORY_SCOPE_AGENT);
  union { unsigned long long u; float2 f; } c; c.u = u;
  return c.f;
}

// bounded RELAXED spin (no per-iteration invalidate): true = flag observed
__device__ __forceinline__ bool wait_flag(unsigned char* f) {
  unsigned n = 0;
  while (__hip_atomic_load(f, __ATOMIC_RELAXED, __HIP_MEMORY_SCOPE_AGENT) == 0) {
    if (++n > SPIN_CAP) return false;
  }
  return true;
}

// ---------------- init: zero the flag arrays each call ----------------

__global__ void init_flags(unsigned* __restrict__ p, int n) {
  int stride = gridDim.x * blockDim.x;
  for (int i = blockIdx.x * blockDim.x + threadIdx.x; i < n; i += stride) p[i] = 0u;
}

// ---------------- persistent GRU pipeline ----------------
// grid: LL*GG = 240 blocks of 256 threads (1 block/CU -> all co-resident).
// Block (l,g) owns ~10-11 of layer l's 512 rows; those rows of all six weight
// matrices live in VGPRs for all 8192 steps. All cross-block publishes are
// ONE coalesced wave-0 store (contiguous dwords, single cache line) followed
// by a release flag store (release's wave-wide vmcnt(0) orders the data).

__launch_bounds__(NTHR, 1)
__global__ void gru_pipeline(
    const float* __restrict__ x,
    const float* __restrict__ Wz, const float* __restrict__ bWz,
    const float* __restrict__ Uz, const float* __restrict__ bUz,
    const float* __restrict__ Wr, const float* __restrict__ bWr,
    const float* __restrict__ Ur, const float* __restrict__ bUr,
    const float* __restrict__ Wh, const float* __restrict__ bWh,
    const float* __restrict__ Uh, const float* __restrict__ bUh,
    float* __restrict__ hring,         // [LL-1][RB][HH]
    float* __restrict__ htop,          // [TT][HH]
    float* __restrict__ rbuf,          // [LL][2][HH]
    unsigned char* __restrict__ rflg,  // [LL][TT][GG]
    unsigned char* __restrict__ hflg,  // [LL][TT][GG]
    float* __restrict__ dout)
{
  const int blk = blockIdx.x;
  const int l = blk / GG;
  const int g = blk % GG;
  const bool ltop = (l == LL - 1);
  const int base = HH / GG;            // 10
  const int rem = HH % GG;             // 32
  const int i0 = g * base + (g < rem ? g : rem);
  const int n_i = base + (g < rem ? 1 : 0);   // 10 or 11

  const int tid = threadIdx.x;
  const int wave = tid >> 6;
  const int lane = tid & 63;
  const int j0 = lane * 8;

  __shared__ float xs[HH];
  __shared__ float hs[HH];
  __shared__ float rh[HH];
  __shared__ float rtmp[16];
  __shared__ float htmp[16];
  __shared__ volatile int dead;        // watchdog latch (anti-hang)
  if (tid == 0) dead = 0;

  // VGPR-resident weights: up to 3 rows per wave (rows r_loc = wave + 4k)
  float wz[3][8], uz[3][8], wr[3][8], ur[3][8], wh[3][8], uh[3][8];
  float bz[3], br[3], bh[3];
  int rowg[3];
  bool act[3];
#pragma unroll
  for (int k = 0; k < 3; ++k) {
    const int rl = wave + 4 * k;
    act[k] = (rl < n_i);
    const int i = i0 + (act[k] ? rl : 0);
    rowg[k] = i;
    if (act[k]) {
      const size_t ro = ((size_t)l * HH + i) * HH + j0;
      *(float4*)&wz[k][0] = *(const float4*)(Wz + ro);
      *(float4*)&wz[k][4] = *(const float4*)(Wz + ro + 4);
      *(float4*)&uz[k][0] = *(const float4*)(Uz + ro);
      *(float4*)&uz[k][4] = *(const float4*)(Uz + ro + 4);
      *(float4*)&wr[k][0] = *(const float4*)(Wr + ro);
      *(float4*)&wr[k][4] = *(const float4*)(Wr + ro + 4);
      *(float4*)&ur[k][0] = *(const float4*)(Ur + ro);
      *(float4*)&ur[k][4] = *(const float4*)(Ur + ro + 4);
      *(float4*)&wh[k][0] = *(const float4*)(Wh + ro);
      *(float4*)&wh[k][4] = *(const float4*)(Wh + ro + 4);
      *(float4*)&uh[k][0] = *(const float4*)(Uh + ro);
      *(float4*)&uh[k][4] = *(const float4*)(Uh + ro + 4);
      bz[k] = bWz[l * HH + i] + bUz[l * HH + i];
      br[k] = bWr[l * HH + i] + bUr[l * HH + i];
      bh[k] = bWh[l * HH + i] + bUh[l * HH + i];
    } else {
      bz[k] = br[k] = bh[k] = 0.f;
#pragma unroll
      for (int q = 0; q < 8; ++q) {
        wz[k][q] = uz[k][q] = wr[k][q] = ur[k][q] = wh[k][q] = uh[k][q] = 0.f;
      }
    }
  }

  unsigned char* my_hflg = hflg + (size_t)l * TT * GG;
  unsigned char* up_hflg = hflg + (size_t)(l > 0 ? l - 1 : 0) * TT * GG;
  unsigned char* dn_hflg = hflg + (size_t)(l < LL - 1 ? l + 1 : l) * TT * GG;
  unsigned char* my_rflg = rflg + (size_t)l * TT * GG;
  float* rb = rbuf + (size_t)l * 2 * HH;
  float* my_ring = hring + (size_t)l * RB * HH;          // valid for l<LL-1
  const float* up_ring = hring + (size_t)(l > 0 ? l - 1 : 0) * RB * HH;

  float zreg[3], awreg[3];
  zreg[0] = zreg[1] = zreg[2] = 0.f;
  awreg[0] = awreg[1] = awreg[2] = 0.f;

  __syncthreads();   // dead=0 visible

  for (int t = 0; t < TT; ++t) {
    // -------- wait for dependencies (relaxed polls, one acquire fence) -----
    if (!dead) {
      if (wave == 0 && l > 0 && lane < GG) {
        if (!wait_flag(up_hflg + (size_t)t * GG + lane)) dead = 1;
      }
      if (wave == 1 && t > 0 && lane < GG) {
        if (!wait_flag(my_hflg + (size_t)(t - 1) * GG + lane)) dead = 1;
      }
      if (wave == 2 && !ltop && t >= RB && lane < GG) {
        if (!wait_flag(dn_hflg + (size_t)(t - RB) * GG + lane)) dead = 1;
      }
    }
    __builtin_amdgcn_fence(__ATOMIC_ACQUIRE, "agent");
    __syncthreads();                                   // S1

    // -------- stage x_in and h_prev into LDS --------
    {
      const int j = tid * 2;
      if (l == 0) {
        const float2 v = *(const float2*)&x[(size_t)t * HH + j];
        xs[j] = v.x; xs[j + 1] = v.y;
      } else {
        const float* src = up_ring + (size_t)(t & (RB - 1)) * HH;
        const float2 v = ld_agent2(&src[j]);
        xs[j] = v.x; xs[j + 1] = v.y;
      }
      if (t == 0) {
        hs[j] = 0.f; hs[j + 1] = 0.f;
      } else {
        const float* src = ltop ? htop + (size_t)(t - 1) * HH
                                : my_ring + (size_t)((t - 1) & (RB - 1)) * HH;
        const float2 v = ld_agent2(&src[j]);
        hs[j] = v.x; hs[j + 1] = v.y;
      }
    }
    __syncthreads();                                   // S2

    float xv[8], hv[8];
    *(float4*)&xv[0] = *(const float4*)&xs[j0];
    *(float4*)&xv[4] = *(const float4*)&xs[j0 + 4];
    *(float4*)&hv[0] = *(const float4*)&hs[j0];
    *(float4*)&hv[4] = *(const float4*)&hs[j0 + 4];

    float* rslot = rb + (size_t)(t & 1) * HH;
    float* hout = ltop ? htop + (size_t)t * HH
                       : my_ring + (size_t)(t & (RB - 1)) * HH;

    if (t == 0) {
      // h_prev = 0: h = z * tanh(Wh x + bh); r irrelevant
#pragma unroll
      for (int k = 0; k < 3; ++k) {
        if (act[k]) {
          float az = 0.f, aw = 0.f;
#pragma unroll
          for (int q = 0; q < 8; ++q) {
            az = fmaf(wz[k][q], xv[q], az);
            aw = fmaf(wh[k][q], xv[q], aw);
          }
          az = wred(az); aw = wred(aw);
          if (lane == 0) {
            htmp[wave + 4 * k] = sigm(az + bz[k]) * tanhf(aw + bh[k]);
          }
        }
      }
      __syncthreads();
      if (wave == 0 && lane < n_i) st_agent(&hout[i0 + lane], htmp[lane]);
      if (tid == 0)
        __hip_atomic_store(&my_hflg[(size_t)0 * GG + g], (unsigned char)1,
                           __ATOMIC_RELEASE, __HIP_MEMORY_SCOPE_AGENT);
      continue;
    }

    // -------- phase 1a: r only (publish ASAP to hide round trip) --------
#pragma unroll
    for (int k = 0; k < 3; ++k) {
      if (act[k]) {
        float ar = 0.f;
#pragma unroll
        for (int q = 0; q < 8; ++q) {
          ar = fmaf(wr[k][q], xv[q], ar);
          ar = fmaf(ur[k][q], hv[q], ar);
        }
        ar = wred(ar);
        if (lane == 0) rtmp[wave + 4 * k] = sigm(ar + br[k]);
      }
    }
    __syncthreads();                                   // S3
    if (wave == 0 && lane < n_i) st_agent(&rslot[i0 + lane], rtmp[lane]);
    if (tid == 0)
      __hip_atomic_store(&my_rflg[(size_t)t * GG + g], (unsigned char)1,
                         __ATOMIC_RELEASE, __HIP_MEMORY_SCOPE_AGENT);

    // -------- phase 1b: z and Wh·x (overlaps the r round trip) --------
#pragma unroll
    for (int k = 0; k < 3; ++k) {
      if (act[k]) {
        float az = 0.f, aw = 0.f;
#pragma unroll
        for (int q = 0; q < 8; ++q) {
          az = fmaf(wz[k][q], xv[q], az);
          az = fmaf(uz[k][q], hv[q], az);
          aw = fmaf(wh[k][q], xv[q], aw);
        }
        az = wred(az); aw = wred(aw);
        if (lane == 0) {
          zreg[k] = sigm(az + bz[k]);
          awreg[k] = aw + bh[k];
        }
      }
    }

    // -------- r barrier across the layer's workgroups --------
    if (!dead && wave == 0 && lane < GG) {
      if (!wait_flag(my_rflg + (size_t)t * GG + lane)) dead = 1;
    }
    __builtin_amdgcn_fence(__ATOMIC_ACQUIRE, "agent");
    __syncthreads();                                   // S4

    // -------- r ⊙ h_prev into LDS --------
    {
      const int j = tid * 2;
      const float2 rv = ld_agent2(&rslot[j]);
      rh[j] = rv.x * hs[j];
      rh[j + 1] = rv.y * hs[j + 1];
    }
    __syncthreads();                                   // S5

    float rhv[8];
    *(float4*)&rhv[0] = *(const float4*)&rh[j0];
    *(float4*)&rhv[4] = *(const float4*)&rh[j0 + 4];

    // -------- phase 2: Uh·(r⊙h), gate combine --------
#pragma unroll
    for (int k = 0; k < 3; ++k) {
      if (act[k]) {
        float u = 0.f;
#pragma unroll
        for (int q = 0; q < 8; ++q) u = fmaf(uh[k][q], rhv[q], u);
        u = wred(u);
        if (lane == 0) {
          const float z = zreg[k];
          const float hp = hs[rowg[k]];
          const float ht = tanhf(awreg[k] + u);
          htmp[wave + 4 * k] = (1.f - z) * hp + z * ht;
        }
      }
    }
    __syncthreads();                                   // S6

    // -------- coalesced h publish + release flag --------
    if (wave == 0 && lane < n_i) st_agent(&hout[i0 + lane], htmp[lane]);
    if (t == TT - 1 && wave == 1 && lane < n_i)
      dout[(size_t)TT * OO + (size_t)l * HH + i0 + lane] = htmp[lane];
    if (tid == 0)
      __hip_atomic_store(&my_hflg[(size_t)t * GG + g], (unsigned char)1,
                         __ATOMIC_RELEASE, __HIP_MEMORY_SCOPE_AGENT);
  }
}

// ---------------- final FC: out[T,O] = outs[T,H] @ fcW[O,H]^T + fcb ----------------

__launch_bounds__(256)
__global__ void fc_gemm(const float* __restrict__ A,   // [TT][HH] (top-layer h)
                        const float* __restrict__ W,   // [OO][HH]
                        const float* __restrict__ bias, // [OO]
                        float* __restrict__ C) {       // [TT][OO]
  __shared__ float As[16][68];
  __shared__ float Ws[16][68];
  const int bm = blockIdx.x;        // TT/64
  const int bn = blockIdx.y;        // OO/64
  const int tid = threadIdx.x;
  const int tx = tid & 15;
  const int ty = tid >> 4;
  const int r = tid >> 2;           // 0..63
  const int kc = (tid & 3) * 4;     // 0,4,8,12
  float acc[4][4];
#pragma unroll
  for (int a = 0; a < 4; ++a)
#pragma unroll
    for (int b2 = 0; b2 < 4; ++b2) acc[a][b2] = 0.f;

  for (int k0 = 0; k0 < HH; k0 += 16) {
    const float4 a4 = *(const float4*)&A[(size_t)(bm * 64 + r) * HH + k0 + kc];
    const float4 w4 = *(const float4*)&W[(size_t)(bn * 64 + r) * HH + k0 + kc];
    __syncthreads();
    As[kc + 0][r] = a4.x; As[kc + 1][r] = a4.y; As[kc + 2][r] = a4.z; As[kc + 3][r] = a4.w;
    Ws[kc + 0][r] = w4.x; Ws[kc + 1][r] = w4.y; Ws[kc + 2][r] = w4.z; Ws[kc + 3][r] = w4.w;
    __syncthreads();
#pragma unroll
    for (int kk = 0; kk < 16; ++kk) {
      const float4 av = *(const float4*)&As[kk][ty * 4];
      const float4 wv = *(const float4*)&Ws[kk][tx * 4];
      const float avv[4] = {av.x, av.y, av.z, av.w};
      const float wvv[4] = {wv.x, wv.y, wv.z, wv.w};
#pragma unroll
      for (int a = 0; a < 4; ++a)
#pragma unroll
        for (int b2 = 0; b2 < 4; ++b2)
          acc[a][b2] = fmaf(avv[a], wvv[b2], acc[a][b2]);
    }
  }
#pragma unroll
  for (int a = 0; a < 4; ++a) {
    const int row = bm * 64 + ty * 4 + a;
#pragma unroll
    for (int b2 = 0; b2 < 4; ++b2) {
      const int col = bn * 64 + tx * 4 + b2;
      C[(size_t)row * OO + col] = acc[a][b2] + bias[col];
    }
  }
}

// ---------------- launch ----------------

extern "C" void kernel_launch(void* const* d_in, const int* in_sizes, int n_in,
                              void* d_out, int out_size, void* d_ws, size_t ws_size,
                              hipStream_t stream) {
  const float* p[15];
  for (int i = 0; i < 15 && i < n_in; ++i) p[i] = (const float*)d_in[i];

  const float *x, *Wz, *bWz, *Uz, *bUz, *Wr, *bWr, *Ur, *bUr, *Wh, *bWh, *Uh, *bUh, *fcW, *fcb;
  x = p[0];
  if (in_sizes[2] == LL * HH) {
    // setup_inputs() dict order: x, Wz, bWz, Uz, bUz, Wr, bWr, Ur, bUr, Wh, bWh, Uh, bUh, fcW, fcb
    Wz = p[1]; bWz = p[2]; Uz = p[3]; bUz = p[4];
    Wr = p[5]; bWr = p[6]; Ur = p[7]; bUr = p[8];
    Wh = p[9]; bWh = p[10]; Uh = p[11]; bUh = p[12];
  } else {
    // signature order fallback: x, Wz, Uz, Wr, Ur, Wh, Uh, bWz, bUz, bWr, bUr, bWh, bUh
    Wz = p[1]; Uz = p[2]; Wr = p[3]; Ur = p[4]; Wh = p[5]; Uh = p[6];
    bWz = p[7]; bUz = p[8]; bWr = p[9]; bUr = p[10]; bWh = p[11]; bUh = p[12];
  }
  fcW = p[13]; fcb = p[14];

  // workspace layout (~20.5 MB total; rings instead of full per-layer history)
  float* hring = (float*)d_ws;                                   // (LL-1)*RB*HH
  float* htop = hring + (size_t)(LL - 1) * RB * HH;              // TT*HH
  float* rbuf = htop + (size_t)TT * HH;                          // LL*2*HH
  unsigned char* rflg = (unsigned char*)(rbuf + (size_t)LL * 2 * HH);  // LL*TT*GG
  unsigned char* hflg = rflg + (size_t)LL * TT * GG;                   // LL*TT*GG

  const int flag_u32 = (int)(2 * (size_t)LL * TT * GG / 4);
  init_flags<<<512, 256, 0, stream>>>((unsigned*)rflg, flag_u32);

  gru_pipeline<<<LL * GG, NTHR, 0, stream>>>(
      x, Wz, bWz, Uz, bUz, Wr, bWr, Ur, bUr, Wh, bWh, Uh, bUh,
      hring, htop, rbuf, rflg, hflg, (float*)d_out);

  fc_gemm<<<dim3(TT / 64, OO / 64), 256, 0, stream>>>(
      htop, fcW, fcb, (float*)d_out);
}

// Round 5
// 45107.217 us; speedup vs baseline: 3.6457x; 3.6380x over previous
//
#include <hip/hip_runtime.h>
#include <math.h>

#define TT 8192
#define HH 512
#define LL 5
#define OO 256
#define GG 48           // workgroups per layer
#define NTHR 256
#define RB 64           // h ring depth (power of 2)
#define CAP_TAG 1000000u
#define CAP_PRG 200000u

typedef unsigned long long u64;
typedef unsigned u32;

// ---------------- helpers ----------------

__device__ __forceinline__ float wred(float v) {
#pragma unroll
  for (int off = 32; off > 0; off >>= 1) v += __shfl_xor(v, off, 64);
  return v;
}

__device__ __forceinline__ float sigm(float v) {
  return 1.0f / (1.0f + expf(-v));
}

__device__ __forceinline__ u64 ldA(const u64* p) {
  return __hip_atomic_load((u64*)p, __ATOMIC_RELAXED, __HIP_MEMORY_SCOPE_AGENT);
}
__device__ __forceinline__ void stA(u64* p, u64 v) {
  __hip_atomic_store(p, v, __ATOMIC_RELAXED, __HIP_MEMORY_SCOPE_AGENT);
}
__device__ __forceinline__ u64 pack(u32 tag, float v) {
  return ((u64)tag << 32) | (u64)__float_as_uint(v);
}

// joint poll of two tagged u64 slots; self-validating (no fences needed)
__device__ __forceinline__ void poll2(const u64* p0, const u64* p1, u32 tag,
                                      volatile int* dead, float& v0, float& v1) {
  u64 a = ldA(p0), b = ldA(p1);
  u32 n = 0;
  while ((u32)(a >> 32) != tag || (u32)(b >> 32) != tag) {
    if (*dead) break;
    if (++n > CAP_TAG) { *dead = 1; break; }
    __builtin_amdgcn_s_sleep(2);
    if ((u32)(a >> 32) != tag) a = ldA(p0);
    if ((u32)(b >> 32) != tag) b = ldA(p1);
  }
  v0 = __uint_as_float((u32)a);
  v1 = __uint_as_float((u32)b);
}

// ---------------- init: zero rings + prog each call ----------------

__global__ void init_ws(u32* __restrict__ p, int n) {
  int stride = gridDim.x * blockDim.x;
  for (int i = blockIdx.x * blockDim.x + threadIdx.x; i < n; i += stride) p[i] = 0u;
}

// ---------------- persistent GRU pipeline ----------------
// LL*GG = 240 blocks of 256 threads (1 block/CU, all co-resident). Block (l,g)
// owns ~10-11 of layer l's 512 rows; their rows of all six weight matrices
// stay in VGPRs for all 8192 steps. ALL cross-block exchange is tagged 64-bit
// relaxed agent atomics (tag = step+1): consumers poll the element itself, so
// no release/acquire fences (-> no per-step L2 writeback/invalidate) anywhere.

__launch_bounds__(NTHR, 1)
__global__ void gru_pipeline(
    const float* __restrict__ x,
    const float* __restrict__ Wz, const float* __restrict__ bWz,
    const float* __restrict__ Uz, const float* __restrict__ bUz,
    const float* __restrict__ Wr, const float* __restrict__ bWr,
    const float* __restrict__ Ur, const float* __restrict__ bUr,
    const float* __restrict__ Wh, const float* __restrict__ bWh,
    const float* __restrict__ Uh, const float* __restrict__ bUh,
    u64* __restrict__ hring,           // [LL][RB][HH] tagged
    u64* __restrict__ rring,           // [LL][2][HH] tagged
    float* __restrict__ htop,          // [TT][HH] plain (FC input)
    u32* __restrict__ prog,            // [LL][GG] completed-step counters
    float* __restrict__ dout)
{
  const int blk = blockIdx.x;
  const int l = blk / GG;
  const int g = blk % GG;
  const bool ltop = (l == LL - 1);
  const int base = HH / GG;            // 10
  const int rem = HH % GG;             // 32
  const int i0 = g * base + (g < rem ? g : rem);
  const int n_i = base + (g < rem ? 1 : 0);   // 10 or 11

  const int tid = threadIdx.x;
  const int wave = tid >> 6;
  const int lane = tid & 63;
  const int j0 = lane * 8;
  const int j = tid * 2;

  __shared__ float xs[HH];
  __shared__ float hs[HH];
  __shared__ float rh[HH];
  __shared__ float rtmp[16];
  __shared__ float htmp[16];
  __shared__ int dead_s;               // watchdog latch (anti-hang)
  volatile int* dead = &dead_s;
  if (tid == 0) dead_s = 0;

  // VGPR-resident weights: up to 3 rows per wave (rows r_loc = wave + 4k)
  float wz[3][8], uz[3][8], wr[3][8], ur[3][8], wh[3][8], uh[3][8];
  float bz[3], br[3], bh[3];
  int rowg[3];
  bool act[3];
#pragma unroll
  for (int k = 0; k < 3; ++k) {
    const int rl = wave + 4 * k;
    act[k] = (rl < n_i);
    const int i = i0 + (act[k] ? rl : 0);
    rowg[k] = i;
    if (act[k]) {
      const size_t ro = ((size_t)l * HH + i) * HH + j0;
      *(float4*)&wz[k][0] = *(const float4*)(Wz + ro);
      *(float4*)&wz[k][4] = *(const float4*)(Wz + ro + 4);
      *(float4*)&uz[k][0] = *(const float4*)(Uz + ro);
      *(float4*)&uz[k][4] = *(const float4*)(Uz + ro + 4);
      *(float4*)&wr[k][0] = *(const float4*)(Wr + ro);
      *(float4*)&wr[k][4] = *(const float4*)(Wr + ro + 4);
      *(float4*)&ur[k][0] = *(const float4*)(Ur + ro);
      *(float4*)&ur[k][4] = *(const float4*)(Ur + ro + 4);
      *(float4*)&wh[k][0] = *(const float4*)(Wh + ro);
      *(float4*)&wh[k][4] = *(const float4*)(Wh + ro + 4);
      *(float4*)&uh[k][0] = *(const float4*)(Uh + ro);
      *(float4*)&uh[k][4] = *(const float4*)(Uh + ro + 4);
      bz[k] = bWz[l * HH + i] + bUz[l * HH + i];
      br[k] = bWr[l * HH + i] + bUr[l * HH + i];
      bh[k] = bWh[l * HH + i] + bUh[l * HH + i];
    } else {
      bz[k] = br[k] = bh[k] = 0.f;
#pragma unroll
      for (int q = 0; q < 8; ++q) {
        wz[k][q] = uz[k][q] = wr[k][q] = ur[k][q] = wh[k][q] = uh[k][q] = 0.f;
      }
    }
  }

  u64* my_h = hring + (size_t)l * RB * HH;
  const u64* up_h = hring + (size_t)(l > 0 ? l - 1 : 0) * RB * HH;
  u64* my_r = rring + (size_t)l * 2 * HH;
  u32* my_prog = prog + l * GG + g;
  u32* dn_prog = prog + (l < LL - 1 ? l + 1 : l) * GG;

  float zreg[3], awreg[3];
  zreg[0] = zreg[1] = zreg[2] = 0.f;
  awreg[0] = awreg[1] = awreg[2] = 0.f;

  __syncthreads();   // dead=0 visible

  for (int t = 0; t < TT; ++t) {
    // -------- stage x_in and h_prev (inline tag polls), back-pressure -------
    if (l == 0) {
      const float2 v = *(const float2*)&x[(size_t)t * HH + j];
      xs[j] = v.x; xs[j + 1] = v.y;
    } else {
      const u64* s = up_h + (size_t)(t & (RB - 1)) * HH + j;
      float a, b;
      poll2(s, s + 1, (u32)(t + 1), dead, a, b);
      xs[j] = a; xs[j + 1] = b;
    }
    if (t == 0) {
      hs[j] = 0.f; hs[j + 1] = 0.f;
    } else {
      const u64* s = my_h + (size_t)((t - 1) & (RB - 1)) * HH + j;
      float a, b;
      poll2(s, s + 1, (u32)t, dead, a, b);
      hs[j] = a; hs[j + 1] = b;
    }
    if (wave == 3 && !ltop && t >= RB && lane < GG) {
      const u32 need = (u32)(t - RB + 1);
      u32 n = 0;
      while (__hip_atomic_load(&dn_prog[lane], __ATOMIC_RELAXED,
                               __HIP_MEMORY_SCOPE_AGENT) < need) {
        if (*dead) break;
        if (++n > CAP_PRG) { *dead = 1; break; }
        __builtin_amdgcn_s_sleep(16);
      }
    }
    __syncthreads();                                   // S2

    float xv[8], hv[8];
    *(float4*)&xv[0] = *(const float4*)&xs[j0];
    *(float4*)&xv[4] = *(const float4*)&xs[j0 + 4];
    *(float4*)&hv[0] = *(const float4*)&hs[j0];
    *(float4*)&hv[4] = *(const float4*)&hs[j0 + 4];

    if (t == 0) {
      // h_prev = 0: h = z * tanh(Wh x + bh)
#pragma unroll
      for (int k = 0; k < 3; ++k) {
        if (act[k]) {
          float az = 0.f, aw = 0.f;
#pragma unroll
          for (int q = 0; q < 8; ++q) {
            az = fmaf(wz[k][q], xv[q], az);
            aw = fmaf(wh[k][q], xv[q], aw);
          }
          az = wred(az); aw = wred(aw);
          if (lane == 0) htmp[wave + 4 * k] = sigm(az + bz[k]) * tanhf(aw + bh[k]);
        }
      }
      __syncthreads();
      if (wave == 0 && lane < n_i)
        stA(&my_h[(size_t)0 * HH + i0 + lane], pack(1u, htmp[lane]));
      if (ltop && wave == 1 && lane < n_i)
        htop[(size_t)0 * HH + i0 + lane] = htmp[lane];
      if (tid == 0)
        __hip_atomic_store(my_prog, 1u, __ATOMIC_RELAXED, __HIP_MEMORY_SCOPE_AGENT);
      continue;
    }

    // -------- phase 1a: r for owned rows, publish immediately --------
#pragma unroll
    for (int k = 0; k < 3; ++k) {
      if (act[k]) {
        float ar = 0.f;
#pragma unroll
        for (int q = 0; q < 8; ++q) {
          ar = fmaf(wr[k][q], xv[q], ar);
          ar = fmaf(ur[k][q], hv[q], ar);
        }
        ar = wred(ar);
        if (lane == 0) rtmp[wave + 4 * k] = sigm(ar + br[k]);
      }
    }
    __syncthreads();                                   // S3
    if (wave == 0 && lane < n_i)
      stA(&my_r[(size_t)(t & 1) * HH + i0 + lane], pack((u32)(t + 1), rtmp[lane]));

    // -------- phase 1b: z and Wh·x (overlaps the r round trip) --------
#pragma unroll
    for (int k = 0; k < 3; ++k) {
      if (act[k]) {
        float az = 0.f, aw = 0.f;
#pragma unroll
        for (int q = 0; q < 8; ++q) {
          az = fmaf(wz[k][q], xv[q], az);
          az = fmaf(uz[k][q], hv[q], az);
          aw = fmaf(wh[k][q], xv[q], aw);
        }
        az = wred(az); aw = wred(aw);
        if (lane == 0) {
          zreg[k] = sigm(az + bz[k]);
          awreg[k] = aw + bh[k];
        }
      }
    }

    // -------- poll r (tagged), build r ⊙ h_prev in LDS --------
    {
      const u64* s = my_r + (size_t)(t & 1) * HH + j;
      float r0, r1;
      poll2(s, s + 1, (u32)(t + 1), dead, r0, r1);
      rh[j] = r0 * hs[j];
      rh[j + 1] = r1 * hs[j + 1];
    }
    __syncthreads();                                   // S5

    float rhv[8];
    *(float4*)&rhv[0] = *(const float4*)&rh[j0];
    *(float4*)&rhv[4] = *(const float4*)&rh[j0 + 4];

    // -------- phase 2: Uh·(r⊙h), gate combine --------
#pragma unroll
    for (int k = 0; k < 3; ++k) {
      if (act[k]) {
        float u = 0.f;
#pragma unroll
        for (int q = 0; q < 8; ++q) u = fmaf(uh[k][q], rhv[q], u);
        u = wred(u);
        if (lane == 0) {
          const float z = zreg[k];
          const float hp = hs[rowg[k]];
          const float ht = tanhf(awreg[k] + u);
          htmp[wave + 4 * k] = (1.f - z) * hp + z * ht;
        }
      }
    }
    __syncthreads();                                   // S6

    // -------- tagged h publish (+ plain htop / final-h) --------
    if (wave == 0 && lane < n_i)
      stA(&my_h[(size_t)(t & (RB - 1)) * HH + i0 + lane], pack((u32)(t + 1), htmp[lane]));
    if (ltop && wave == 1 && lane < n_i)
      htop[(size_t)t * HH + i0 + lane] = htmp[lane];
    if (t == TT - 1 && wave == 2 && lane < n_i)
      dout[(size_t)TT * OO + (size_t)l * HH + i0 + lane] = htmp[lane];
    if (tid == 0)
      __hip_atomic_store(my_prog, (u32)(t + 1), __ATOMIC_RELAXED, __HIP_MEMORY_SCOPE_AGENT);
  }
}

// ---------------- final FC: out[T,O] = outs[T,H] @ fcW[O,H]^T + fcb ----------------

__launch_bounds__(256)
__global__ void fc_gemm(const float* __restrict__ A,   // [TT][HH] (top-layer h)
                        const float* __restrict__ W,   // [OO][HH]
                        const float* __restrict__ bias, // [OO]
                        float* __restrict__ C) {       // [TT][OO]
  __shared__ float As[16][68];
  __shared__ float Ws[16][68];
  const int bm = blockIdx.x;        // TT/64
  const int bn = blockIdx.y;        // OO/64
  const int tid = threadIdx.x;
  const int tx = tid & 15;
  const int ty = tid >> 4;
  const int r = tid >> 2;           // 0..63
  const int kc = (tid & 3) * 4;     // 0,4,8,12
  float acc[4][4];
#pragma unroll
  for (int a = 0; a < 4; ++a)
#pragma unroll
    for (int b2 = 0; b2 < 4; ++b2) acc[a][b2] = 0.f;

  for (int k0 = 0; k0 < HH; k0 += 16) {
    const float4 a4 = *(const float4*)&A[(size_t)(bm * 64 + r) * HH + k0 + kc];
    const float4 w4 = *(const float4*)&W[(size_t)(bn * 64 + r) * HH + k0 + kc];
    __syncthreads();
    As[kc + 0][r] = a4.x; As[kc + 1][r] = a4.y; As[kc + 2][r] = a4.z; As[kc + 3][r] = a4.w;
    Ws[kc + 0][r] = w4.x; Ws[kc + 1][r] = w4.y; Ws[kc + 2][r] = w4.z; Ws[kc + 3][r] = w4.w;
    __syncthreads();
#pragma unroll
    for (int kk = 0; kk < 16; ++kk) {
      const float4 av = *(const float4*)&As[kk][ty * 4];
      const float4 wv = *(const float4*)&Ws[kk][tx * 4];
      const float avv[4] = {av.x, av.y, av.z, av.w};
      const float wvv[4] = {wv.x, wv.y, wv.z, wv.w};
#pragma unroll
      for (int a = 0; a < 4; ++a)
#pragma unroll
        for (int b2 = 0; b2 < 4; ++b2)
          acc[a][b2] = fmaf(avv[a], wvv[b2], acc[a][b2]);
    }
  }
#pragma unroll
  for (int a = 0; a < 4; ++a) {
    const int row = bm * 64 + ty * 4 + a;
#pragma unroll
    for (int b2 = 0; b2 < 4; ++b2) {
      const int col = bn * 64 + tx * 4 + b2;
      C[(size_t)row * OO + col] = acc[a][b2] + bias[col];
    }
  }
}

// ---------------- launch ----------------

extern "C" void kernel_launch(void* const* d_in, const int* in_sizes, int n_in,
                              void* d_out, int out_size, void* d_ws, size_t ws_size,
                              hipStream_t stream) {
  const float* p[15];
  for (int i = 0; i < 15 && i < n_in; ++i) p[i] = (const float*)d_in[i];

  const float *x, *Wz, *bWz, *Uz, *bUz, *Wr, *bWr, *Ur, *bUr, *Wh, *bWh, *Uh, *bUh, *fcW, *fcb;
  x = p[0];
  if (in_sizes[2] == LL * HH) {
    // setup_inputs() dict order: x, Wz, bWz, Uz, bUz, Wr, bWr, Ur, bUr, Wh, bWh, Uh, bUh, fcW, fcb
    Wz = p[1]; bWz = p[2]; Uz = p[3]; bUz = p[4];
    Wr = p[5]; bWr = p[6]; Ur = p[7]; bUr = p[8];
    Wh = p[9]; bWh = p[10]; Uh = p[11]; bUh = p[12];
  } else {
    // signature order fallback
    Wz = p[1]; Uz = p[2]; Wr = p[3]; Ur = p[4]; Wh = p[5]; Uh = p[6];
    bWz = p[7]; bUz = p[8]; bWr = p[9]; bUr = p[10]; bWh = p[11]; bUh = p[12];
  }
  fcW = p[13]; fcb = p[14];

  // workspace layout: [hring u64 LL*RB*HH | rring u64 LL*2*HH | prog u32 LL*GG | htop f32 TT*HH]
  u64* hring = (u64*)d_ws;
  u64* rring = hring + (size_t)LL * RB * HH;
  u32* prog = (u32*)(rring + (size_t)LL * 2 * HH);
  float* htop = (float*)(prog + (size_t)LL * GG);

  const int zero_u32 = (int)(((size_t)LL * RB * HH + (size_t)LL * 2 * HH) * 2 + LL * GG);
  init_ws<<<512, 256, 0, stream>>>((u32*)d_ws, zero_u32);

  gru_pipeline<<<LL * GG, NTHR, 0, stream>>>(
      x, Wz, bWz, Uz, bUz, Wr, bWr, Ur, bUr, Wh, bWh, Uh, bUh,
      hring, rring, htop, prog, (float*)d_out);

  fc_gemm<<<dim3(TT / 64, OO / 64), 256, 0, stream>>>(
      htop, fcW, fcb, (float*)d_out);
}